// Round 1
// baseline (1976.913 us; speedup 1.0000x reference)
//
#include <hip/hip_runtime.h>
#include <hip/hip_bf16.h>

typedef __bf16 bf16x8 __attribute__((ext_vector_type(8)));
typedef float f32x4 __attribute__((ext_vector_type(4)));

#define MFMA_BF16(a,b,c) __builtin_amdgcn_mfma_f32_16x16x32_bf16(a,b,c,0,0,0)

__device__ __forceinline__ unsigned short f2bf(float f) {
  unsigned u = __builtin_bit_cast(unsigned, f);
  return (unsigned short)((u + 0x7FFFu + ((u >> 16) & 1u)) >> 16);
}

// ---------------- 128x128 tile GEMM, BK=32, 256 threads (4 waves 2x2) ---------
// C[row][col] = sum_k A[row][k] * B[k][col], accumulation f32, inputs bf16-ized.
// A_BF16: A is bf16 (else f32, converted during staging). B always f32.
// ROPE: apply GPT-J interleaved rotary to q/k region of the 12288-wide output.
// OUT_BF16: store bf16 (else f32).
template<bool A_BF16, bool ROPE, bool OUT_BF16>
__global__ __launch_bounds__(256)
void gemm128(const void* __restrict__ Ap, const float* __restrict__ Bp,
             const int* __restrict__ pos, void* __restrict__ Cp,
             int N, int K)
{
  // stride 40 (80B): A-frag/B-frag b128 reads are ~2-way (free); 16B aligned.
  __shared__ __align__(16) short Al[128*40];
  __shared__ __align__(16) short Bl[128*40];
  const int tid = threadIdx.x;
  const int lane = tid & 63, wid = tid >> 6;
  const int wr = wid >> 1, wc = wid & 1;
  const int row0 = blockIdx.y * 128, col0 = blockIdx.x * 128;
  f32x4 acc[4][4] = {};

  const int bcol = tid & 127;
  const int kb0 = (tid >> 7) * 4;   // 0 or 4

  for (int kt = 0; kt < K; kt += 32) {
    // ---- stage A (128 x 32) ----
    if (A_BF16) {
      const unsigned short* Ab = (const unsigned short*)Ap;
      for (int i = 0; i < 2; ++i) {
        int idx = tid + i*256;
        int ar = idx >> 2, ac = (idx & 3) * 8;
        *(int4*)(&Al[ar*40 + ac]) = *(const int4*)(Ab + (size_t)(row0+ar)*K + kt + ac);
      }
    } else {
      const float* Af = (const float*)Ap;
      for (int i = 0; i < 4; ++i) {
        int idx = tid + i*256;
        int ar = idx >> 3, ac = (idx & 7) * 4;
        float4 v = *(const float4*)(Af + (size_t)(row0+ar)*K + kt + ac);
        short4 h;
        h.x = (short)f2bf(v.x); h.y = (short)f2bf(v.y);
        h.z = (short)f2bf(v.z); h.w = (short)f2bf(v.w);
        *(short4*)(&Al[ar*40 + ac]) = h;
      }
    }
    // ---- stage B transposed: Bl[col][k] (32 x 128 -> [128][32]) ----
    for (int r = 0; r < 4; ++r) {
      int kb = kb0 + r*8;
      const float* bp = Bp + (size_t)(kt+kb)*N + col0 + bcol;
      float x0 = bp[0];
      float x1 = bp[(size_t)N];
      float x2 = bp[2*(size_t)N];
      float x3 = bp[3*(size_t)N];
      short4 h;
      h.x = (short)f2bf(x0); h.y = (short)f2bf(x1);
      h.z = (short)f2bf(x2); h.w = (short)f2bf(x3);
      *(short4*)(&Bl[bcol*40 + kb]) = h;
    }
    __syncthreads();
    // ---- compute: one K=32 mfma per (m,n) frag ----
    const int k8 = (lane >> 4) * 8;
    bf16x8 af[4], bfr[4];
    for (int m = 0; m < 4; ++m)
      af[m] = *(const bf16x8*)(&Al[(wr*64 + m*16 + (lane&15))*40 + k8]);
    for (int n = 0; n < 4; ++n)
      bfr[n] = *(const bf16x8*)(&Bl[(wc*64 + n*16 + (lane&15))*40 + k8]);
    for (int m = 0; m < 4; ++m)
      for (int n = 0; n < 4; ++n)
        acc[m][n] = MFMA_BF16(af[m], bfr[n], acc[m][n]);
    __syncthreads();
  }

  // ---- epilogue: C/D layout row = 4*(lane>>4)+r, col = lane&15 ----
  for (int m = 0; m < 4; ++m) {
    const int rbase = row0 + wr*64 + m*16 + ((lane>>4)<<2);
    for (int n = 0; n < 4; ++n) {
      const int c = col0 + wc*64 + n*16 + (lane & 15);
      bool rot = false;
      float invf = 0.f;
      if (ROPE) {
        // rotary iff within first 64 dims of a q or k head (cols < 8192).
        // c0 (frag base) is 16-aligned; 64-wide region is 64-aligned -> wave-uniform.
        rot = (c < 8192) && ((c & 255) < 64);
        if (rot) {
          int i2 = (c & 63) >> 1;
          // inv_freq = 10000^(-2i/64) = 2^(-i * log2(1e4)/32)
          invf = exp2f(-(float)i2 * 0.4152410118609203f);
        }
      }
      for (int r = 0; r < 4; ++r) {
        int rowg = rbase + r;
        float v = acc[m][n][r];
        if (ROPE) {
          if (rot) {
            float ang = (float)pos[rowg] * invf;
            float s_ = __sinf(ang), c_ = __cosf(ang);
            float pv = __shfl_xor(v, 1, 64);
            // even col: x1*cos - x2*sin ; odd col: x2*cos + x1*sin
            v = (c & 1) ? fmaf(v, c_, pv * s_) : fmaf(v, c_, -pv * s_);
          }
        }
        if (OUT_BF16)
          ((unsigned short*)Cp)[(size_t)rowg*N + c] = f2bf(v);
        else
          ((float*)Cp)[(size_t)rowg*N + c] = v;
      }
    }
  }
}

// ---------------- flash attention: 64 q-rows / block, 4 waves x 16 rows -------
__global__ __launch_bounds__(256)
void attn_kernel(const unsigned short* __restrict__ qkv,
                 unsigned short* __restrict__ ctx)
{
  const int S = 2048, D = 256, QN = 12288;
  __shared__ __align__(16) unsigned char Kl[64*512];    // [64][256] bf16, XOR-swizzled
  __shared__ __align__(16) unsigned char Vl[256*128];   // Vt [256 d][64 k] bf16, XOR-swizzled
  __shared__ __align__(16) unsigned char Pl[64*144];    // P [64][64] bf16, stride 72
  const int tid = threadIdx.x, lane = tid & 63, w = tid >> 6;
  const int qt = blockIdx.x, bh = blockIdx.y;
  const int b = bh >> 4, h = bh & 15;
  const size_t rowbase = (size_t)b * S;
  const int colr = lane & 15, g = lane >> 4;

  // Q A-frags held in registers for the whole kernel: qf[st] covers d = 32*st + 8g .. +8
  bf16x8 qf[8];
  {
    const unsigned short* qp = qkv + (rowbase + qt*64 + w*16 + colr)*QN + h*D + g*8;
    for (int f = 0; f < 8; ++f)
      qf[f] = *(const bf16x8*)(qp + 32*f);
  }
  f32x4 acc[16] = {};
  float m_r[4], l_r[4];
  for (int r = 0; r < 4; ++r) { m_r[r] = -1e30f; l_r[r] = 0.f; }

  for (int kt = 0; kt <= qt; ++kt) {
    // ---- stage K tile [64][256], swizzle byte ^= (row&7)<<4 ----
    {
      const unsigned short* kbase = qkv + (rowbase + kt*64)*QN + 4096 + h*D;
      for (int i = 0; i < 8; ++i) {
        int idx = tid + i*256;
        int kr = idx >> 5, c8 = (idx & 31) * 8;
        bf16x8 v = *(const bf16x8*)(kbase + (size_t)kr*QN + c8);
        *(bf16x8*)(Kl + ((kr*512 + c8*2) ^ ((kr & 7) << 4))) = v;
      }
    }
    // ---- stage V transposed: Vt[d][k] = V[k][d], swizzle byte ^= (d&7)<<4 ----
    {
      const unsigned short* vbase = qkv + (rowbase + kt*64)*QN + 8192 + h*D;
      int dd = (tid >> 2) * 4;        // 0..252
      int kbb = (tid & 3) * 4;        // 0,4,8,12
      for (int r4 = 0; r4 < 4; ++r4) {
        int kb = kbb + 16*r4;
        short4 v0 = *(const short4*)(vbase + (size_t)(kb+0)*QN + dd);
        short4 v1 = *(const short4*)(vbase + (size_t)(kb+1)*QN + dd);
        short4 v2 = *(const short4*)(vbase + (size_t)(kb+2)*QN + dd);
        short4 v3 = *(const short4*)(vbase + (size_t)(kb+3)*QN + dd);
        short4 t;
        t.x=v0.x; t.y=v1.x; t.z=v2.x; t.w=v3.x;
        *(short4*)(Vl + (((dd+0)*128 + kb*2) ^ (((dd+0)&7)<<4))) = t;
        t.x=v0.y; t.y=v1.y; t.z=v2.y; t.w=v3.y;
        *(short4*)(Vl + (((dd+1)*128 + kb*2) ^ (((dd+1)&7)<<4))) = t;
        t.x=v0.z; t.y=v1.z; t.z=v2.z; t.w=v3.z;
        *(short4*)(Vl + (((dd+2)*128 + kb*2) ^ (((dd+2)&7)<<4))) = t;
        t.x=v0.w; t.y=v1.w; t.z=v2.w; t.w=v3.w;
        *(short4*)(Vl + (((dd+3)*128 + kb*2) ^ (((dd+3)&7)<<4))) = t;
      }
    }
    __syncthreads();

    // ---- QK^T: sc[nf] = Q(16 rows) x K^T(16 cols), K-dim = 256 ----
    f32x4 sc[4];
    for (int nf = 0; nf < 4; ++nf) {
      f32x4 s = {};
      int krow = nf*16 + colr;
      int xo = (krow & 7) << 4;
      const unsigned char* kp = Kl + krow*512;
      for (int st = 0; st < 8; ++st) {
        bf16x8 kf = *(const bf16x8*)(kp + (((64*st + 16*g)) ^ xo));
        s = MFMA_BF16(qf[st], kf, s);
      }
      sc[nf] = s;
    }

    // ---- online softmax over the 64 k-cols of this tile ----
    const int qrow0 = qt*64 + w*16 + g*4;
    float pm[4] = {-3e38f,-3e38f,-3e38f,-3e38f};
    float pvv[4][4];
    for (int nf = 0; nf < 4; ++nf) {
      int kcol = kt*64 + nf*16 + colr;
      for (int r = 0; r < 4; ++r) {
        float v = sc[nf][r] * 0.0625f;          // 1/sqrt(256)
        if (kcol > qrow0 + r) v = -1e30f;       // causal mask
        pvv[nf][r] = v;
        pm[r] = fmaxf(pm[r], v);
      }
    }
    for (int mk = 1; mk < 16; mk <<= 1)
      for (int r = 0; r < 4; ++r)
        pm[r] = fmaxf(pm[r], __shfl_xor(pm[r], mk, 64));
    float alpha[4];
    for (int r = 0; r < 4; ++r) {
      float mn = fmaxf(m_r[r], pm[r]);
      alpha[r] = __expf(m_r[r] - mn);
      m_r[r] = mn;
    }
    float ps[4] = {0.f,0.f,0.f,0.f};
    unsigned short pb[4][4];
    for (int nf = 0; nf < 4; ++nf)
      for (int r = 0; r < 4; ++r) {
        float p = __expf(pvv[nf][r] - m_r[r]);  // masked -> exp(-1e30 - m) = 0
        ps[r] += p;
        pb[nf][r] = f2bf(p);
      }
    for (int mk = 1; mk < 16; mk <<= 1)
      for (int r = 0; r < 4; ++r)
        ps[r] += __shfl_xor(ps[r], mk, 64);
    for (int r = 0; r < 4; ++r)
      l_r[r] = l_r[r]*alpha[r] + ps[r];
    for (int nf2 = 0; nf2 < 16; ++nf2)
      for (int r = 0; r < 4; ++r)
        acc[nf2][r] *= alpha[r];

    // ---- P (C-layout) -> LDS -> A-layout frags ----
    for (int nf = 0; nf < 4; ++nf)
      for (int r = 0; r < 4; ++r)
        *(unsigned short*)(Pl + (w*16 + g*4 + r)*144 + (nf*16 + colr)*2) = pb[nf][r];
    __syncthreads();

    // ---- PV: acc[nf2] += P(16x64) x V(64 x 16-col slice) ----
    for (int st2 = 0; st2 < 2; ++st2) {
      bf16x8 pf = *(const bf16x8*)(Pl + (w*16 + colr)*144 + (32*st2 + g*8)*2);
      for (int nf2 = 0; nf2 < 16; ++nf2) {
        int d = nf2*16 + colr;
        bf16x8 vf = *(const bf16x8*)(Vl + ((d*128 + 64*st2 + 16*g) ^ ((d&7)<<4)));
        acc[nf2] = MFMA_BF16(pf, vf, acc[nf2]);
      }
    }
    __syncthreads();
  }

  // ---- write ctx bf16 [B,S,H] ----
  float linv[4];
  for (int r = 0; r < 4; ++r) linv[r] = 1.0f / l_r[r];
  for (int nf2 = 0; nf2 < 16; ++nf2)
    for (int r = 0; r < 4; ++r) {
      int qrow = qt*64 + w*16 + g*4 + r;
      float o = acc[nf2][r] * linv[r];
      ctx[(rowbase + qrow)*4096 + h*D + nf2*16 + colr] = f2bf(o);
    }
}

extern "C" void kernel_launch(void* const* d_in, const int* in_sizes, int n_in,
                              void* d_out, int out_size, void* d_ws, size_t ws_size,
                              hipStream_t stream) {
  const int*   pos    = (const int*)d_in[0];
  const float* hidden = (const float*)d_in[1];
  const float* Wqkv   = (const float*)d_in[2];
  const float* Wo     = (const float*)d_in[3];

  // workspace: qkv bf16 [4096][12288], ctx bf16 [4096][4096]
  const size_t QKV_ELEMS = (size_t)4096 * 12288;
  const size_t CTX_ELEMS = (size_t)4096 * 4096;
  if (ws_size < (QKV_ELEMS + CTX_ELEMS) * 2) return;  // visible failure, no corruption
  unsigned short* qkv = (unsigned short*)d_ws;
  unsigned short* ctx = qkv + QKV_ELEMS;

  // GEMM1: qkv = hidden @ Wqkv, + fused GPT-J RoPE, bf16 out
  gemm128<false, true, true><<<dim3(96, 32), 256, 0, stream>>>(
      hidden, Wqkv, pos, qkv, 12288, 4096);
  // flash attention (causal), bf16 ctx out
  attn_kernel<<<dim3(32, 32), 256, 0, stream>>>(qkv, ctx);
  // GEMM2: out = ctx @ Wo, f32 out
  gemm128<true, false, false><<<dim3(32, 32), 256, 0, stream>>>(
      ctx, Wo, nullptr, d_out, 4096, 4096);
}

// Round 2
// 1460.438 us; speedup vs baseline: 1.3536x; 1.3536x over previous
//
#include <hip/hip_runtime.h>
#include <hip/hip_bf16.h>

typedef __bf16 bf16x8 __attribute__((ext_vector_type(8)));
typedef float f32x4 __attribute__((ext_vector_type(4)));

#define MFMA_BF16(a,b,c) __builtin_amdgcn_mfma_f32_16x16x32_bf16(a,b,c,0,0,0)

#define GLOAD16(g, l) __builtin_amdgcn_global_load_lds( \
    (const __attribute__((address_space(1))) unsigned int*)(g), \
    (__attribute__((address_space(3))) unsigned int*)(l), 16, 0, 0)

__device__ __forceinline__ unsigned short f2bf(float f) {
  unsigned u = __builtin_bit_cast(unsigned, f);
  return (unsigned short)((u + 0x7FFFu + ((u >> 16) & 1u)) >> 16);
}

// ---------------- pre-pass: f32 -> bf16 vectorized convert --------------------
__global__ __launch_bounds__(256)
void convert_bf16(const float* __restrict__ src, unsigned short* __restrict__ dst,
                  int n8) {
  int i = blockIdx.x * blockDim.x + threadIdx.x;
  int stride = gridDim.x * blockDim.x;
  for (; i < n8; i += stride) {
    float4 a = ((const float4*)src)[i*2];
    float4 b = ((const float4*)src)[i*2 + 1];
    short4 h0, h1;
    h0.x = (short)f2bf(a.x); h0.y = (short)f2bf(a.y);
    h0.z = (short)f2bf(a.z); h0.w = (short)f2bf(a.w);
    h1.x = (short)f2bf(b.x); h1.y = (short)f2bf(b.y);
    h1.z = (short)f2bf(b.z); h1.w = (short)f2bf(b.w);
    ((short4*)dst)[i*2] = h0;
    ((short4*)dst)[i*2 + 1] = h1;
  }
}

// ---------------- pre-pass: W [K][N] f32 -> Wt [N][K] bf16 --------------------
__global__ __launch_bounds__(256)
void transpose_convert(const float* __restrict__ W, unsigned short* __restrict__ Wt,
                       int K, int N) {
  __shared__ float tl[64][65];
  const int k0 = blockIdx.y * 64, n0 = blockIdx.x * 64;
  const int tr = threadIdx.x >> 4;          // 0..15
  const int tc4 = (threadIdx.x & 15) * 4;   // 0..60
  for (int i = 0; i < 4; ++i) {
    int r = tr + i*16;
    float4 v = *(const float4*)(W + (size_t)(k0 + r)*N + n0 + tc4);
    tl[r][tc4+0] = v.x; tl[r][tc4+1] = v.y;
    tl[r][tc4+2] = v.z; tl[r][tc4+3] = v.w;
  }
  __syncthreads();
  for (int i = 0; i < 4; ++i) {
    int nr = tr + i*16;
    short4 h;
    h.x = (short)f2bf(tl[tc4+0][nr]);
    h.y = (short)f2bf(tl[tc4+1][nr]);
    h.z = (short)f2bf(tl[tc4+2][nr]);
    h.w = (short)f2bf(tl[tc4+3][nr]);
    *(short4*)(Wt + (size_t)(n0 + nr)*K + k0 + tc4) = h;
  }
}

// ---------------- fast GEMM: both operands bf16, global_load_lds staging ------
// A [M][K] bf16 row-major, Bt [N][K] bf16 (i.e. B transposed), C [M][N].
// 128x128 tile, BK=64, 256 threads (4 waves 2x2), m201-style XOR swizzle:
// linear LDS dest + inverse-swizzled global src + swizzled ds_read (rule #21).
template<bool ROPE, bool OUT_BF16>
__global__ __launch_bounds__(256)
void gemm_fast(const unsigned short* __restrict__ A,
               const unsigned short* __restrict__ Bt,
               const int* __restrict__ pos,
               void* __restrict__ Cp, int N, int K, int nbx)
{
  __shared__ __align__(16) unsigned short Al[128*64];
  __shared__ __align__(16) unsigned short Bl[128*64];
  const int tid = threadIdx.x, lane = tid & 63, wid = tid >> 6;
  const int wr = wid >> 1, wc = wid & 1;
  // XCD-aware block swizzle (nwg % 8 == 0 for all our grids)
  const int nwg = gridDim.x;
  int wg = blockIdx.x;
  if ((nwg & 7) == 0) wg = (wg & 7) * (nwg >> 3) + (wg >> 3);
  const int bx = wg % nbx, by = wg / nbx;
  const int row0 = by * 128, col0 = bx * 128;

  f32x4 acc[4][4] = {};
  const int crow = lane & 15, g = lane >> 4;
  // staging: lane l covers chunk-row l>>3; source seg inverse-swizzled
  const int arow = lane >> 3;                      // 0..7 within 8-row chunk
  const int asegsw = ((lane & 7) ^ arow) * 8;      // bf16 elems, pre-swizzled src
  const int xo = (crow & 7) << 4;                  // read-side XOR (bytes)

  for (int kt = 0; kt < K; kt += 64) {
    for (int c = 0; c < 4; ++c) {
      int ch = wid * 4 + c;                        // 0..15
      int r = ch * 8 + arow;                       // tile row / tile col 0..127
      GLOAD16(A  + (size_t)(row0 + r)*K + kt + asegsw, &Al[ch*512]);
      GLOAD16(Bt + (size_t)(col0 + r)*K + kt + asegsw, &Bl[ch*512]);
    }
    __syncthreads();
    for (int kk = 0; kk < 2; ++kk) {
      const int ko = (kk*64 + g*16) ^ xo;          // byte offset within 128B row
      bf16x8 af[4], bfr[4];
      for (int m = 0; m < 4; ++m)
        af[m] = *(const bf16x8*)((const char*)Al + (wr*64 + m*16 + crow)*128 + ko);
      for (int n = 0; n < 4; ++n)
        bfr[n] = *(const bf16x8*)((const char*)Bl + (wc*64 + n*16 + crow)*128 + ko);
      for (int m = 0; m < 4; ++m)
        for (int n = 0; n < 4; ++n)
          acc[m][n] = MFMA_BF16(af[m], bfr[n], acc[m][n]);
    }
    __syncthreads();
  }

  // epilogue: C/D layout row = 4*(lane>>4)+r, col = lane&15
  for (int m = 0; m < 4; ++m) {
    const int rbase = row0 + wr*64 + m*16 + (g << 2);
    for (int n = 0; n < 4; ++n) {
      const int c = col0 + wc*64 + n*16 + crow;
      bool rot = false;
      float invf = 0.f;
      if (ROPE) {
        rot = (c < 8192) && ((c & 255) < 64);
        if (rot) {
          int i2 = (c & 63) >> 1;
          invf = exp2f(-(float)i2 * 0.4152410118609203f);
        }
      }
      for (int r = 0; r < 4; ++r) {
        int rowg = rbase + r;
        float v = acc[m][n][r];
        if (ROPE && rot) {
          float ang = (float)pos[rowg] * invf;
          float s_ = __sinf(ang), c_ = __cosf(ang);
          float pv = __shfl_xor(v, 1, 64);
          v = (c & 1) ? fmaf(v, c_, pv * s_) : fmaf(v, c_, -pv * s_);
        }
        if (OUT_BF16)
          ((unsigned short*)Cp)[(size_t)rowg*N + c] = f2bf(v);
        else
          ((float*)Cp)[(size_t)rowg*N + c] = v;
      }
    }
  }
}

// ---------------- fallback GEMM (round-1): handles f32 operands in-loop -------
template<bool A_BF16, bool ROPE, bool OUT_BF16>
__global__ __launch_bounds__(256)
void gemm128(const void* __restrict__ Ap, const float* __restrict__ Bp,
             const int* __restrict__ pos, void* __restrict__ Cp,
             int N, int K)
{
  __shared__ __align__(16) short Al[128*40];
  __shared__ __align__(16) short Bl[128*40];
  const int tid = threadIdx.x;
  const int lane = tid & 63, wid = tid >> 6;
  const int wr = wid >> 1, wc = wid & 1;
  const int row0 = blockIdx.y * 128, col0 = blockIdx.x * 128;
  f32x4 acc[4][4] = {};
  const int bcol = tid & 127;
  const int kb0 = (tid >> 7) * 4;

  for (int kt = 0; kt < K; kt += 32) {
    if (A_BF16) {
      const unsigned short* Ab = (const unsigned short*)Ap;
      for (int i = 0; i < 2; ++i) {
        int idx = tid + i*256;
        int ar = idx >> 2, ac = (idx & 3) * 8;
        *(int4*)(&Al[ar*40 + ac]) = *(const int4*)(Ab + (size_t)(row0+ar)*K + kt + ac);
      }
    } else {
      const float* Af = (const float*)Ap;
      for (int i = 0; i < 4; ++i) {
        int idx = tid + i*256;
        int ar = idx >> 3, ac = (idx & 7) * 4;
        float4 v = *(const float4*)(Af + (size_t)(row0+ar)*K + kt + ac);
        short4 h;
        h.x = (short)f2bf(v.x); h.y = (short)f2bf(v.y);
        h.z = (short)f2bf(v.z); h.w = (short)f2bf(v.w);
        *(short4*)(&Al[ar*40 + ac]) = h;
      }
    }
    for (int r = 0; r < 4; ++r) {
      int kb = kb0 + r*8;
      const float* bp = Bp + (size_t)(kt+kb)*N + col0 + bcol;
      float x0 = bp[0];
      float x1 = bp[(size_t)N];
      float x2 = bp[2*(size_t)N];
      float x3 = bp[3*(size_t)N];
      short4 h;
      h.x = (short)f2bf(x0); h.y = (short)f2bf(x1);
      h.z = (short)f2bf(x2); h.w = (short)f2bf(x3);
      *(short4*)(&Bl[bcol*40 + kb]) = h;
    }
    __syncthreads();
    const int k8 = (lane >> 4) * 8;
    bf16x8 af[4], bfr[4];
    for (int m = 0; m < 4; ++m)
      af[m] = *(const bf16x8*)(&Al[(wr*64 + m*16 + (lane&15))*40 + k8]);
    for (int n = 0; n < 4; ++n)
      bfr[n] = *(const bf16x8*)(&Bl[(wc*64 + n*16 + (lane&15))*40 + k8]);
    for (int m = 0; m < 4; ++m)
      for (int n = 0; n < 4; ++n)
        acc[m][n] = MFMA_BF16(af[m], bfr[n], acc[m][n]);
    __syncthreads();
  }

  for (int m = 0; m < 4; ++m) {
    const int rbase = row0 + wr*64 + m*16 + ((lane>>4)<<2);
    for (int n = 0; n < 4; ++n) {
      const int c = col0 + wc*64 + n*16 + (lane & 15);
      bool rot = false;
      float invf = 0.f;
      if (ROPE) {
        rot = (c < 8192) && ((c & 255) < 64);
        if (rot) {
          int i2 = (c & 63) >> 1;
          invf = exp2f(-(float)i2 * 0.4152410118609203f);
        }
      }
      for (int r = 0; r < 4; ++r) {
        int rowg = rbase + r;
        float v = acc[m][n][r];
        if (ROPE && rot) {
          float ang = (float)pos[rowg] * invf;
          float s_ = __sinf(ang), c_ = __cosf(ang);
          float pv = __shfl_xor(v, 1, 64);
          v = (c & 1) ? fmaf(v, c_, pv * s_) : fmaf(v, c_, -pv * s_);
        }
        if (OUT_BF16)
          ((unsigned short*)Cp)[(size_t)rowg*N + c] = f2bf(v);
        else
          ((float*)Cp)[(size_t)rowg*N + c] = v;
      }
    }
  }
}

// ---------------- flash attention: 64 q-rows / block, 4 waves x 16 rows -------
__global__ __launch_bounds__(256)
void attn_kernel(const unsigned short* __restrict__ qkv,
                 unsigned short* __restrict__ ctx)
{
  const int S = 2048, D = 256, QN = 12288;
  __shared__ __align__(16) unsigned char Kl[64*512];
  __shared__ __align__(16) unsigned char Vl[256*128];
  __shared__ __align__(16) unsigned char Pl[64*144];
  const int tid = threadIdx.x, lane = tid & 63, w = tid >> 6;
  const int qt = blockIdx.x, bh = blockIdx.y;
  const int b = bh >> 4, h = bh & 15;
  const size_t rowbase = (size_t)b * S;
  const int colr = lane & 15, g = lane >> 4;

  bf16x8 qf[8];
  {
    const unsigned short* qp = qkv + (rowbase + qt*64 + w*16 + colr)*QN + h*D + g*8;
    for (int f = 0; f < 8; ++f)
      qf[f] = *(const bf16x8*)(qp + 32*f);
  }
  f32x4 acc[16] = {};
  float m_r[4], l_r[4];
  for (int r = 0; r < 4; ++r) { m_r[r] = -1e30f; l_r[r] = 0.f; }

  for (int kt = 0; kt <= qt; ++kt) {
    {
      const unsigned short* kbase = qkv + (rowbase + kt*64)*QN + 4096 + h*D;
      for (int i = 0; i < 8; ++i) {
        int idx = tid + i*256;
        int kr = idx >> 5, c8 = (idx & 31) * 8;
        bf16x8 v = *(const bf16x8*)(kbase + (size_t)kr*QN + c8);
        *(bf16x8*)(Kl + ((kr*512 + c8*2) ^ ((kr & 7) << 4))) = v;
      }
    }
    {
      const unsigned short* vbase = qkv + (rowbase + kt*64)*QN + 8192 + h*D;
      int dd = (tid >> 2) * 4;
      int kbb = (tid & 3) * 4;
      for (int r4 = 0; r4 < 4; ++r4) {
        int kb = kbb + 16*r4;
        short4 v0 = *(const short4*)(vbase + (size_t)(kb+0)*QN + dd);
        short4 v1 = *(const short4*)(vbase + (size_t)(kb+1)*QN + dd);
        short4 v2 = *(const short4*)(vbase + (size_t)(kb+2)*QN + dd);
        short4 v3 = *(const short4*)(vbase + (size_t)(kb+3)*QN + dd);
        short4 t;
        t.x=v0.x; t.y=v1.x; t.z=v2.x; t.w=v3.x;
        *(short4*)(Vl + (((dd+0)*128 + kb*2) ^ (((dd+0)&7)<<4))) = t;
        t.x=v0.y; t.y=v1.y; t.z=v2.y; t.w=v3.y;
        *(short4*)(Vl + (((dd+1)*128 + kb*2) ^ (((dd+1)&7)<<4))) = t;
        t.x=v0.z; t.y=v1.z; t.z=v2.z; t.w=v3.z;
        *(short4*)(Vl + (((dd+2)*128 + kb*2) ^ (((dd+2)&7)<<4))) = t;
        t.x=v0.w; t.y=v1.w; t.z=v2.w; t.w=v3.w;
        *(short4*)(Vl + (((dd+3)*128 + kb*2) ^ (((dd+3)&7)<<4))) = t;
      }
    }
    __syncthreads();

    f32x4 sc[4];
    for (int nf = 0; nf < 4; ++nf) {
      f32x4 s = {};
      int krow = nf*16 + colr;
      int xo2 = (krow & 7) << 4;
      const unsigned char* kp = Kl + krow*512;
      for (int st = 0; st < 8; ++st) {
        bf16x8 kf = *(const bf16x8*)(kp + (((64*st + 16*g)) ^ xo2));
        s = MFMA_BF16(qf[st], kf, s);
      }
      sc[nf] = s;
    }

    const int qrow0 = qt*64 + w*16 + g*4;
    float pm[4] = {-3e38f,-3e38f,-3e38f,-3e38f};
    float pvv[4][4];
    for (int nf = 0; nf < 4; ++nf) {
      int kcol = kt*64 + nf*16 + colr;
      for (int r = 0; r < 4; ++r) {
        float v = sc[nf][r] * 0.0625f;
        if (kcol > qrow0 + r) v = -1e30f;
        pvv[nf][r] = v;
        pm[r] = fmaxf(pm[r], v);
      }
    }
    for (int mk = 1; mk < 16; mk <<= 1)
      for (int r = 0; r < 4; ++r)
        pm[r] = fmaxf(pm[r], __shfl_xor(pm[r], mk, 64));
    float alpha[4];
    for (int r = 0; r < 4; ++r) {
      float mn = fmaxf(m_r[r], pm[r]);
      alpha[r] = __expf(m_r[r] - mn);
      m_r[r] = mn;
    }
    float ps[4] = {0.f,0.f,0.f,0.f};
    unsigned short pb[4][4];
    for (int nf = 0; nf < 4; ++nf)
      for (int r = 0; r < 4; ++r) {
        float p = __expf(pvv[nf][r] - m_r[r]);
        ps[r] += p;
        pb[nf][r] = f2bf(p);
      }
    for (int mk = 1; mk < 16; mk <<= 1)
      for (int r = 0; r < 4; ++r)
        ps[r] += __shfl_xor(ps[r], mk, 64);
    for (int r = 0; r < 4; ++r)
      l_r[r] = l_r[r]*alpha[r] + ps[r];
    for (int nf2 = 0; nf2 < 16; ++nf2)
      for (int r = 0; r < 4; ++r)
        acc[nf2][r] *= alpha[r];

    for (int nf = 0; nf < 4; ++nf)
      for (int r = 0; r < 4; ++r)
        *(unsigned short*)(Pl + (w*16 + g*4 + r)*144 + (nf*16 + colr)*2) = pb[nf][r];
    __syncthreads();

    for (int st2 = 0; st2 < 2; ++st2) {
      bf16x8 pf = *(const bf16x8*)(Pl + (w*16 + colr)*144 + (32*st2 + g*8)*2);
      for (int nf2 = 0; nf2 < 16; ++nf2) {
        int d = nf2*16 + colr;
        bf16x8 vf = *(const bf16x8*)(Vl + ((d*128 + 64*st2 + 16*g) ^ ((d&7)<<4)));
        acc[nf2] = MFMA_BF16(pf, vf, acc[nf2]);
      }
    }
    __syncthreads();
  }

  float linv[4];
  for (int r = 0; r < 4; ++r) linv[r] = 1.0f / l_r[r];
  for (int nf2 = 0; nf2 < 16; ++nf2)
    for (int r = 0; r < 4; ++r) {
      int qrow = qt*64 + w*16 + g*4 + r;
      float o = acc[nf2][r] * linv[r];
      ctx[(rowbase + qrow)*4096 + h*D + nf2*16 + colr] = f2bf(o);
    }
}

extern "C" void kernel_launch(void* const* d_in, const int* in_sizes, int n_in,
                              void* d_out, int out_size, void* d_ws, size_t ws_size,
                              hipStream_t stream) {
  const int*   pos    = (const int*)d_in[0];
  const float* hidden = (const float*)d_in[1];
  const float* Wqkv   = (const float*)d_in[2];
  const float* Wo     = (const float*)d_in[3];

  const size_t QKV_B  = (size_t)4096 * 12288 * 2;   // 100,663,296
  const size_t CTX_B  = (size_t)4096 * 4096 * 2;    //  33,554,432
  const size_t FAST_NEED = QKV_B + QKV_B + CTX_B;   // 234,881,024

  if (ws_size >= FAST_NEED) {
    // ---- fast path: bf16 pre-pass + global_load_lds GEMMs ----
    unsigned short* qkv     = (unsigned short*)d_ws;
    unsigned short* WqkvT   = (unsigned short*)((char*)d_ws + QKV_B);
    unsigned short* WoT     = WqkvT;                                   // after GEMM1
    unsigned short* ctx     = (unsigned short*)((char*)d_ws + QKV_B + CTX_B);
    unsigned short* hiddenB = (unsigned short*)((char*)d_ws + 2*QKV_B);

    convert_bf16<<<2048, 256, 0, stream>>>(hidden, hiddenB, 4096*4096/8);
    transpose_convert<<<dim3(192, 64), 256, 0, stream>>>(Wqkv, WqkvT, 4096, 12288);
    gemm_fast<true, true><<<3072, 256, 0, stream>>>(
        hiddenB, WqkvT, pos, qkv, 12288, 4096, 96);
    transpose_convert<<<dim3(64, 64), 256, 0, stream>>>(Wo, WoT, 4096, 4096);
    attn_kernel<<<dim3(32, 32), 256, 0, stream>>>(qkv, ctx);
    gemm_fast<false, false><<<1024, 256, 0, stream>>>(
        ctx, WoT, nullptr, d_out, 4096, 4096, 32);
  } else {
    // ---- fallback: round-1 path (needs 134 MB) ----
    if (ws_size < QKV_B + CTX_B) return;
    unsigned short* qkv = (unsigned short*)d_ws;
    unsigned short* ctx = qkv + (size_t)4096 * 12288;
    gemm128<false, true, true><<<dim3(96, 32), 256, 0, stream>>>(
        hidden, Wqkv, pos, qkv, 12288, 4096);
    attn_kernel<<<dim3(32, 32), 256, 0, stream>>>(qkv, ctx);
    gemm128<true, false, false><<<dim3(32, 32), 256, 0, stream>>>(
        ctx, Wo, nullptr, d_out, 4096, 4096);
  }
}

// Round 3
// 1230.003 us; speedup vs baseline: 1.6072x; 1.1873x over previous
//
#include <hip/hip_runtime.h>
#include <hip/hip_bf16.h>

typedef __bf16 bf16x8 __attribute__((ext_vector_type(8)));
typedef float f32x4 __attribute__((ext_vector_type(4)));

#define MFMA_BF16(a,b,c) __builtin_amdgcn_mfma_f32_16x16x32_bf16(a,b,c,0,0,0)

#define GLOAD16(g, l) __builtin_amdgcn_global_load_lds( \
    (const __attribute__((address_space(1))) unsigned int*)(g), \
    (__attribute__((address_space(3))) unsigned int*)(l), 16, 0, 0)

__device__ __forceinline__ unsigned short f2bf(float f) {
  unsigned u = __builtin_bit_cast(unsigned, f);
  return (unsigned short)((u + 0x7FFFu + ((u >> 16) & 1u)) >> 16);
}

// ---------------- pre-pass: f32 -> bf16 vectorized convert --------------------
__global__ __launch_bounds__(256)
void convert_bf16(const float* __restrict__ src, unsigned short* __restrict__ dst,
                  int n8) {
  int i = blockIdx.x * blockDim.x + threadIdx.x;
  int stride = gridDim.x * blockDim.x;
  for (; i < n8; i += stride) {
    float4 a = ((const float4*)src)[i*2];
    float4 b = ((const float4*)src)[i*2 + 1];
    short4 h0, h1;
    h0.x = (short)f2bf(a.x); h0.y = (short)f2bf(a.y);
    h0.z = (short)f2bf(a.z); h0.w = (short)f2bf(a.w);
    h1.x = (short)f2bf(b.x); h1.y = (short)f2bf(b.y);
    h1.z = (short)f2bf(b.z); h1.w = (short)f2bf(b.w);
    ((short4*)dst)[i*2] = h0;
    ((short4*)dst)[i*2 + 1] = h1;
  }
}

// ---------------- pre-pass: W [K][N] f32 -> Wt [N][K] bf16 --------------------
__global__ __launch_bounds__(256)
void transpose_convert(const float* __restrict__ W, unsigned short* __restrict__ Wt,
                       int K, int N) {
  __shared__ float tl[64][65];
  const int k0 = blockIdx.y * 64, n0 = blockIdx.x * 64;
  const int tr = threadIdx.x >> 4;
  const int tc4 = (threadIdx.x & 15) * 4;
  for (int i = 0; i < 4; ++i) {
    int r = tr + i*16;
    float4 v = *(const float4*)(W + (size_t)(k0 + r)*N + n0 + tc4);
    tl[r][tc4+0] = v.x; tl[r][tc4+1] = v.y;
    tl[r][tc4+2] = v.z; tl[r][tc4+3] = v.w;
  }
  __syncthreads();
  for (int i = 0; i < 4; ++i) {
    int nr = tr + i*16;
    short4 h;
    h.x = (short)f2bf(tl[tc4+0][nr]);
    h.y = (short)f2bf(tl[tc4+1][nr]);
    h.z = (short)f2bf(tl[tc4+2][nr]);
    h.w = (short)f2bf(tl[tc4+3][nr]);
    *(short4*)(Wt + (size_t)(n0 + nr)*K + k0 + tc4) = h;
  }
}

// ---------------- 256x256 GEMM, BK=64, 8 waves, counted-vmcnt pipeline --------
// A [M][K] bf16, Bt [N][K] bf16 (B transposed), C [M][N].
// LDS: 2 buffers x 4 slabs (Ah0,Ah1,Bh0,Bh1) x [128 rows][64 k] bf16 = 128 KiB.
// Both-sides XOR swizzle (rule #21): linear gload_lds dest + inverse-swizzled
// global source + swizzled ds_read. Raw s_barrier + vmcnt(8) (never 0 in loop):
// 2 K-tiles in flight; stage(t+2) issued into buf freed after all waves' reads.
template<bool ROPE, bool OUT_BF16>
__global__ __launch_bounds__(512, 2)
void gemm256(const unsigned short* __restrict__ A,
             const unsigned short* __restrict__ Bt,
             const int* __restrict__ pos,
             void* __restrict__ Cp, int N, int K, int nbx)
{
  __shared__ __align__(16) unsigned short L[2][4][8192];
  const int tid = threadIdx.x, lane = tid & 63, w = tid >> 6;
  const int wr = w >> 2, wc = w & 3;
  const int nwg = gridDim.x;
  int wg = blockIdx.x;
  if ((nwg & 7) == 0) wg = (wg & 7) * (nwg >> 3) + (wg >> 3);   // XCD swizzle
  const int bx = wg % nbx, by = wg / nbx;
  const int row0 = by * 256, col0 = bx * 256;

  const int crow = lane & 15, g = lane >> 4;
  const int arow = lane >> 3;                       // row within 8-row chunk
  const int asegsw = ((lane & 7) ^ arow) * 8;       // inverse-swizzled src seg
  const int xo = (crow & 7) << 4;                   // read-side XOR (bytes)

  // per-thread 32-bit global offsets (ushort units) for 4 A- and 4 B-chunks
  unsigned aoff[4], boff[4];
#pragma unroll
  for (int i = 0; i < 4; ++i) {
    int chunk = w*4 + i;                            // 0..31 (8 rows each)
    aoff[i] = (unsigned)((row0 + chunk*8 + arow) * K + asegsw);
    boff[i] = (unsigned)((col0 + chunk*8 + arow) * K + asegsw);
  }

#define STAGE(T, B) do {                                              \
    int kto = (T) * 64;                                               \
    _Pragma("unroll")                                                 \
    for (int i = 0; i < 4; ++i) {                                     \
      GLOAD16(A  + aoff[i] + kto, &L[B][wr][(wc*4 + i)*512]);         \
      GLOAD16(Bt + boff[i] + kto, &L[B][2 + wr][(wc*4 + i)*512]);     \
    }                                                                 \
  } while (0)

  f32x4 acc[8][4] = {};
  const int nt = K >> 6;
  // prologue: 2 K-tiles in flight
  STAGE(0, 0);
  STAGE(1, 1);
  int cur = 0;

  for (int t = 0; t < nt; ++t) {
    if (t < nt - 1) asm volatile("s_waitcnt vmcnt(8)" ::: "memory");
    else            asm volatile("s_waitcnt vmcnt(0)" ::: "memory");
    __builtin_amdgcn_s_barrier();                   // tile t visible to all

    const char* Ab = (const char*)&L[cur][wr][0];
    const char* Bb = (const char*)&L[cur][2 + (wc >> 1)][0];
    const int rB0 = (wc & 1) * 64;

    __builtin_amdgcn_s_setprio(1);
    bf16x8 af[2][8], bfv[2][4];
#pragma unroll
    for (int kk = 0; kk < 2; ++kk) {
      const int ko = (((kk*4 + g) << 4)) ^ xo;
#pragma unroll
      for (int m = 0; m < 8; ++m)
        af[kk][m] = *(const bf16x8*)(Ab + (m*16 + crow)*128 + ko);
#pragma unroll
      for (int n = 0; n < 4; ++n)
        bfv[kk][n] = *(const bf16x8*)(Bb + (rB0 + n*16 + crow)*128 + ko);
    }
#pragma unroll
    for (int kk = 0; kk < 2; ++kk)
#pragma unroll
      for (int m = 0; m < 8; ++m)
#pragma unroll
        for (int n = 0; n < 4; ++n)
          acc[m][n] = MFMA_BF16(af[kk][m], bfv[kk][n], acc[m][n]);
    __builtin_amdgcn_s_setprio(0);

    __builtin_amdgcn_sched_barrier(0);
    asm volatile("s_waitcnt lgkmcnt(0)" ::: "memory");  // my LDS reads done
    __builtin_amdgcn_sched_barrier(0);
    __builtin_amdgcn_s_barrier();                   // ALL waves' reads done
    if (t + 2 < nt) STAGE(t + 2, cur);              // overwrite freed buffer
    cur ^= 1;
  }
#undef STAGE

  // ---- epilogue: C/D layout row = 4g+r, col = crow ----
#pragma unroll
  for (int m = 0; m < 8; ++m) {
    const int rbase = row0 + wr*128 + m*16 + (g << 2);
#pragma unroll
    for (int n = 0; n < 4; ++n) {
      const int c = col0 + wc*64 + n*16 + crow;
      bool rot = false;
      float invf = 0.f;
      if (ROPE) {
        rot = (c < 8192) && ((c & 255) < 64);
        if (rot) {
          int i2 = (c & 63) >> 1;
          invf = exp2f(-(float)i2 * 0.4152410118609203f);
        }
      }
#pragma unroll
      for (int r = 0; r < 4; ++r) {
        int rowg = rbase + r;
        float v = acc[m][n][r];
        if (ROPE && rot) {
          float ang = (float)pos[rowg] * invf;
          float s_ = __sinf(ang), c_ = __cosf(ang);
          float pv = __shfl_xor(v, 1, 64);
          v = (c & 1) ? fmaf(v, c_, pv * s_) : fmaf(v, c_, -pv * s_);
        }
        if (OUT_BF16)
          ((unsigned short*)Cp)[(size_t)rowg*N + c] = f2bf(v);
        else
          ((float*)Cp)[(size_t)rowg*N + c] = v;
      }
    }
  }
}

// ---------------- fallback GEMM (round-1): handles f32 operands in-loop -------
template<bool A_BF16, bool ROPE, bool OUT_BF16>
__global__ __launch_bounds__(256)
void gemm128(const void* __restrict__ Ap, const float* __restrict__ Bp,
             const int* __restrict__ pos, void* __restrict__ Cp,
             int N, int K)
{
  __shared__ __align__(16) short Al[128*40];
  __shared__ __align__(16) short Bl[128*40];
  const int tid = threadIdx.x;
  const int lane = tid & 63, wid = tid >> 6;
  const int wr = wid >> 1, wc = wid & 1;
  const int row0 = blockIdx.y * 128, col0 = blockIdx.x * 128;
  f32x4 acc[4][4] = {};
  const int bcol = tid & 127;
  const int kb0 = (tid >> 7) * 4;

  for (int kt = 0; kt < K; kt += 32) {
    if (A_BF16) {
      const unsigned short* Ab = (const unsigned short*)Ap;
      for (int i = 0; i < 2; ++i) {
        int idx = tid + i*256;
        int ar = idx >> 2, ac = (idx & 3) * 8;
        *(int4*)(&Al[ar*40 + ac]) = *(const int4*)(Ab + (size_t)(row0+ar)*K + kt + ac);
      }
    } else {
      const float* Af = (const float*)Ap;
      for (int i = 0; i < 4; ++i) {
        int idx = tid + i*256;
        int ar = idx >> 3, ac = (idx & 7) * 4;
        float4 v = *(const float4*)(Af + (size_t)(row0+ar)*K + kt + ac);
        short4 h;
        h.x = (short)f2bf(v.x); h.y = (short)f2bf(v.y);
        h.z = (short)f2bf(v.z); h.w = (short)f2bf(v.w);
        *(short4*)(&Al[ar*40 + ac]) = h;
      }
    }
    for (int r = 0; r < 4; ++r) {
      int kb = kb0 + r*8;
      const float* bp = Bp + (size_t)(kt+kb)*N + col0 + bcol;
      float x0 = bp[0];
      float x1 = bp[(size_t)N];
      float x2 = bp[2*(size_t)N];
      float x3 = bp[3*(size_t)N];
      short4 h;
      h.x = (short)f2bf(x0); h.y = (short)f2bf(x1);
      h.z = (short)f2bf(x2); h.w = (short)f2bf(x3);
      *(short4*)(&Bl[bcol*40 + kb]) = h;
    }
    __syncthreads();
    const int k8 = (lane >> 4) * 8;
    bf16x8 af[4], bfr[4];
    for (int m = 0; m < 4; ++m)
      af[m] = *(const bf16x8*)(&Al[(wr*64 + m*16 + (lane&15))*40 + k8]);
    for (int n = 0; n < 4; ++n)
      bfr[n] = *(const bf16x8*)(&Bl[(wc*64 + n*16 + (lane&15))*40 + k8]);
    for (int m = 0; m < 4; ++m)
      for (int n = 0; n < 4; ++n)
        acc[m][n] = MFMA_BF16(af[m], bfr[n], acc[m][n]);
    __syncthreads();
  }

  for (int m = 0; m < 4; ++m) {
    const int rbase = row0 + wr*64 + m*16 + ((lane>>4)<<2);
    for (int n = 0; n < 4; ++n) {
      const int c = col0 + wc*64 + n*16 + (lane & 15);
      bool rot = false;
      float invf = 0.f;
      if (ROPE) {
        rot = (c < 8192) && ((c & 255) < 64);
        if (rot) {
          int i2 = (c & 63) >> 1;
          invf = exp2f(-(float)i2 * 0.4152410118609203f);
        }
      }
      for (int r = 0; r < 4; ++r) {
        int rowg = rbase + r;
        float v = acc[m][n][r];
        if (ROPE && rot) {
          float ang = (float)pos[rowg] * invf;
          float s_ = __sinf(ang), c_ = __cosf(ang);
          float pv = __shfl_xor(v, 1, 64);
          v = (c & 1) ? fmaf(v, c_, pv * s_) : fmaf(v, c_, -pv * s_);
        }
        if (OUT_BF16)
          ((unsigned short*)Cp)[(size_t)rowg*N + c] = f2bf(v);
        else
          ((float*)Cp)[(size_t)rowg*N + c] = v;
      }
    }
  }
}

// ---------------- flash attention: 64 q-rows / block, 4 waves x 16 rows -------
__global__ __launch_bounds__(256)
void attn_kernel(const unsigned short* __restrict__ qkv,
                 unsigned short* __restrict__ ctx)
{
  const int S = 2048, D = 256, QN = 12288;
  __shared__ __align__(16) unsigned char Kl[64*512];
  __shared__ __align__(16) unsigned char Vl[256*128];
  __shared__ __align__(16) unsigned char Pl[64*144];
  const int tid = threadIdx.x, lane = tid & 63, w = tid >> 6;
  const int qt = blockIdx.x, bh = blockIdx.y;
  const int b = bh >> 4, h = bh & 15;
  const size_t rowbase = (size_t)b * S;
  const int colr = lane & 15, g = lane >> 4;

  bf16x8 qf[8];
  {
    const unsigned short* qp = qkv + (rowbase + qt*64 + w*16 + colr)*QN + h*D + g*8;
    for (int f = 0; f < 8; ++f)
      qf[f] = *(const bf16x8*)(qp + 32*f);
  }
  f32x4 acc[16] = {};
  float m_r[4], l_r[4];
  for (int r = 0; r < 4; ++r) { m_r[r] = -1e30f; l_r[r] = 0.f; }

  for (int kt = 0; kt <= qt; ++kt) {
    {
      const unsigned short* kbase = qkv + (rowbase + kt*64)*QN + 4096 + h*D;
      for (int i = 0; i < 8; ++i) {
        int idx = tid + i*256;
        int kr = idx >> 5, c8 = (idx & 31) * 8;
        bf16x8 v = *(const bf16x8*)(kbase + (size_t)kr*QN + c8);
        *(bf16x8*)(Kl + ((kr*512 + c8*2) ^ ((kr & 7) << 4))) = v;
      }
    }
    {
      const unsigned short* vbase = qkv + (rowbase + kt*64)*QN + 8192 + h*D;
      int dd = (tid >> 2) * 4;
      int kbb = (tid & 3) * 4;
      for (int r4 = 0; r4 < 4; ++r4) {
        int kb = kbb + 16*r4;
        short4 v0 = *(const short4*)(vbase + (size_t)(kb+0)*QN + dd);
        short4 v1 = *(const short4*)(vbase + (size_t)(kb+1)*QN + dd);
        short4 v2 = *(const short4*)(vbase + (size_t)(kb+2)*QN + dd);
        short4 v3 = *(const short4*)(vbase + (size_t)(kb+3)*QN + dd);
        short4 t;
        t.x=v0.x; t.y=v1.x; t.z=v2.x; t.w=v3.x;
        *(short4*)(Vl + (((dd+0)*128 + kb*2) ^ (((dd+0)&7)<<4))) = t;
        t.x=v0.y; t.y=v1.y; t.z=v2.y; t.w=v3.y;
        *(short4*)(Vl + (((dd+1)*128 + kb*2) ^ (((dd+1)&7)<<4))) = t;
        t.x=v0.z; t.y=v1.z; t.z=v2.z; t.w=v3.z;
        *(short4*)(Vl + (((dd+2)*128 + kb*2) ^ (((dd+2)&7)<<4))) = t;
        t.x=v0.w; t.y=v1.w; t.z=v2.w; t.w=v3.w;
        *(short4*)(Vl + (((dd+3)*128 + kb*2) ^ (((dd+3)&7)<<4))) = t;
      }
    }
    __syncthreads();

    f32x4 sc[4];
    for (int nf = 0; nf < 4; ++nf) {
      f32x4 s = {};
      int krow = nf*16 + colr;
      int xo2 = (krow & 7) << 4;
      const unsigned char* kp = Kl + krow*512;
      for (int st = 0; st < 8; ++st) {
        bf16x8 kf = *(const bf16x8*)(kp + (((64*st + 16*g)) ^ xo2));
        s = MFMA_BF16(qf[st], kf, s);
      }
      sc[nf] = s;
    }

    const int qrow0 = qt*64 + w*16 + g*4;
    float pm[4] = {-3e38f,-3e38f,-3e38f,-3e38f};
    float pvv[4][4];
    for (int nf = 0; nf < 4; ++nf) {
      int kcol = kt*64 + nf*16 + colr;
      for (int r = 0; r < 4; ++r) {
        float v = sc[nf][r] * 0.0625f;
        if (kcol > qrow0 + r) v = -1e30f;
        pvv[nf][r] = v;
        pm[r] = fmaxf(pm[r], v);
      }
    }
    for (int mk = 1; mk < 16; mk <<= 1)
      for (int r = 0; r < 4; ++r)
        pm[r] = fmaxf(pm[r], __shfl_xor(pm[r], mk, 64));
    float alpha[4];
    for (int r = 0; r < 4; ++r) {
      float mn = fmaxf(m_r[r], pm[r]);
      alpha[r] = __expf(m_r[r] - mn);
      m_r[r] = mn;
    }
    float ps[4] = {0.f,0.f,0.f,0.f};
    unsigned short pb[4][4];
    for (int nf = 0; nf < 4; ++nf)
      for (int r = 0; r < 4; ++r) {
        float p = __expf(pvv[nf][r] - m_r[r]);
        ps[r] += p;
        pb[nf][r] = f2bf(p);
      }
    for (int mk = 1; mk < 16; mk <<= 1)
      for (int r = 0; r < 4; ++r)
        ps[r] += __shfl_xor(ps[r], mk, 64);
    for (int r = 0; r < 4; ++r)
      l_r[r] = l_r[r]*alpha[r] + ps[r];
    for (int nf2 = 0; nf2 < 16; ++nf2)
      for (int r = 0; r < 4; ++r)
        acc[nf2][r] *= alpha[r];

    for (int nf = 0; nf < 4; ++nf)
      for (int r = 0; r < 4; ++r)
        *(unsigned short*)(Pl + (w*16 + g*4 + r)*144 + (nf*16 + colr)*2) = pb[nf][r];
    __syncthreads();

    for (int st2 = 0; st2 < 2; ++st2) {
      bf16x8 pf = *(const bf16x8*)(Pl + (w*16 + colr)*144 + (32*st2 + g*8)*2);
      for (int nf2 = 0; nf2 < 16; ++nf2) {
        int d = nf2*16 + colr;
        bf16x8 vf = *(const bf16x8*)(Vl + ((d*128 + 64*st2 + 16*g) ^ ((d&7)<<4)));
        acc[nf2] = MFMA_BF16(pf, vf, acc[nf2]);
      }
    }
    __syncthreads();
  }

  float linv[4];
  for (int r = 0; r < 4; ++r) linv[r] = 1.0f / l_r[r];
  for (int nf2 = 0; nf2 < 16; ++nf2)
    for (int r = 0; r < 4; ++r) {
      int qrow = qt*64 + w*16 + g*4 + r;
      float o = acc[nf2][r] * linv[r];
      ctx[(rowbase + qrow)*4096 + h*D + nf2*16 + colr] = f2bf(o);
    }
}

extern "C" void kernel_launch(void* const* d_in, const int* in_sizes, int n_in,
                              void* d_out, int out_size, void* d_ws, size_t ws_size,
                              hipStream_t stream) {
  const int*   pos    = (const int*)d_in[0];
  const float* hidden = (const float*)d_in[1];
  const float* Wqkv   = (const float*)d_in[2];
  const float* Wo     = (const float*)d_in[3];

  const size_t QKV_B  = (size_t)4096 * 12288 * 2;
  const size_t CTX_B  = (size_t)4096 * 4096 * 2;
  const size_t FAST_NEED = QKV_B + QKV_B + CTX_B;

  if (ws_size >= FAST_NEED) {
    unsigned short* qkv     = (unsigned short*)d_ws;
    unsigned short* WqkvT   = (unsigned short*)((char*)d_ws + QKV_B);
    unsigned short* WoT     = WqkvT;                               // after GEMM1
    unsigned short* ctx     = (unsigned short*)((char*)d_ws + QKV_B + CTX_B);
    unsigned short* hiddenB = (unsigned short*)((char*)d_ws + 2*QKV_B);

    convert_bf16<<<2048, 256, 0, stream>>>(hidden, hiddenB, 4096*4096/8);
    transpose_convert<<<dim3(192, 64), 256, 0, stream>>>(Wqkv, WqkvT, 4096, 12288);
    gemm256<true, true><<<768, 512, 0, stream>>>(
        hiddenB, WqkvT, pos, qkv, 12288, 4096, 48);
    transpose_convert<<<dim3(64, 64), 256, 0, stream>>>(Wo, WoT, 4096, 4096);
    attn_kernel<<<dim3(32, 32), 256, 0, stream>>>(qkv, ctx);
    gemm256<false, false><<<256, 512, 0, stream>>>(
        ctx, WoT, nullptr, d_out, 4096, 4096, 16);
  } else {
    if (ws_size < QKV_B + CTX_B) return;
    unsigned short* qkv = (unsigned short*)d_ws;
    unsigned short* ctx = qkv + (size_t)4096 * 12288;
    gemm128<false, true, true><<<dim3(96, 32), 256, 0, stream>>>(
        hidden, Wqkv, pos, qkv, 12288, 4096);
    attn_kernel<<<dim3(32, 32), 256, 0, stream>>>(qkv, ctx);
    gemm128<true, false, false><<<dim3(32, 32), 256, 0, stream>>>(
        ctx, Wo, nullptr, d_out, 4096, 4096);
  }
}